// Round 1
// baseline (5696.038 us; speedup 1.0000x reference)
//
#include <hip/hip_runtime.h>
#include <cstdint>
#include <cstddef>

#define H      128
#define IN_    12
#define GATES  512   // 4*H
#define B_     256
#define T_     2048
#define TCMAX  2048
#define TS     32    // layer-1 sub-chunk (gx1 batch)

// d_ws layout (floats):
//   [0, B_*tc*H)        hs0 chunk buffer (layer-0 hidden history)
//   [+0, B_*2*H)        layer-0 (h,c) state
//   [+0, B_*2*H)        layer-1 (h,c) state

__device__ __forceinline__ float sigmoidf_(float x) {
    return 1.f / (1.f + __expf(-x));
}
__device__ __forceinline__ float tanhf_(float x) {
    return 2.f / (1.f + __expf(-2.f * x)) - 1.f;
}

// ---------------- Layer 0 scan over one chunk ----------------
__global__ __launch_bounds__(512, 2) void lstm_l0(
    const float* __restrict__ x, const float* __restrict__ Wih,
    const float* __restrict__ Whh, const float* __restrict__ bih,
    const float* __restrict__ bhh, float* __restrict__ hs0,
    float* __restrict__ state, int tc, int chunk)
{
    const int b = blockIdx.x;
    const int g = threadIdx.x;   // gate row 0..511

    __shared__ alignas(16) float sh_x[TCMAX * IN_];  // up to 96 KB
    __shared__ alignas(16) float sh_h[H];
    __shared__ alignas(16) float sh_act[GATES];

    // resident weights: one full row of W_hh (128 f32 regs) + W_ih row (12)
    float wh[H];
    const float4* wr = (const float4*)(Whh + (size_t)g * H);
#pragma unroll
    for (int k = 0; k < H / 4; ++k) {
        float4 v = wr[k];
        wh[4*k] = v.x; wh[4*k+1] = v.y; wh[4*k+2] = v.z; wh[4*k+3] = v.w;
    }
    float wi[IN_];
    const float4* wr2 = (const float4*)(Wih + (size_t)g * IN_);
#pragma unroll
    for (int k = 0; k < IN_ / 4; ++k) {
        float4 v = wr2[k];
        wi[4*k] = v.x; wi[4*k+1] = v.y; wi[4*k+2] = v.z; wi[4*k+3] = v.w;
    }
    const float bias = bih[g] + bhh[g];

    // stage this chunk's x rows (contiguous, coalesced)
    const float* xs = x + ((size_t)b * T_ + (size_t)chunk * tc) * IN_;
    for (int i = g; i < tc * IN_; i += 512) sh_x[i] = xs[i];

    float hreg = 0.f, creg = 0.f;
    if (g < H) {
        if (chunk) { hreg = state[b * 2 * H + g]; creg = state[b * 2 * H + H + g]; }
        sh_h[g] = hreg;
    }
    __syncthreads();

    float* hs_out = hs0 + (size_t)b * tc * H;

    for (int t = 0; t < tc; ++t) {
        float a0 = bias, a1 = 0.f, a2 = 0.f, a3 = 0.f;
        // input projection (12 wide)
        const float4* xh = (const float4*)(sh_x + t * IN_);
        {
            float4 v = xh[0];
            a0 = fmaf(wi[0], v.x, a0); a1 = fmaf(wi[1], v.y, a1);
            a2 = fmaf(wi[2], v.z, a2); a3 = fmaf(wi[3], v.w, a3);
            v = xh[1];
            a0 = fmaf(wi[4], v.x, a0); a1 = fmaf(wi[5], v.y, a1);
            a2 = fmaf(wi[6], v.z, a2); a3 = fmaf(wi[7], v.w, a3);
            v = xh[2];
            a0 = fmaf(wi[8], v.x, a0); a1 = fmaf(wi[9], v.y, a1);
            a2 = fmaf(wi[10], v.z, a2); a3 = fmaf(wi[11], v.w, a3);
        }
        // recurrent matvec: broadcast LDS reads of h
        const float4* h4 = (const float4*)sh_h;
#pragma unroll
        for (int k = 0; k < H / 4; ++k) {
            float4 v = h4[k];
            a0 = fmaf(wh[4*k],   v.x, a0); a1 = fmaf(wh[4*k+1], v.y, a1);
            a2 = fmaf(wh[4*k+2], v.z, a2); a3 = fmaf(wh[4*k+3], v.w, a3);
        }
        float pre = (a0 + a1) + (a2 + a3);
        // gate order i,f,g,o: rows [256,384) use tanh — wave-uniform branch
        float act = ((g >> 7) == 2) ? tanhf_(pre) : sigmoidf_(pre);
        sh_act[g] = act;
        __syncthreads();
        if (g < H) {
            creg = fmaf(sh_act[H + g], creg, sh_act[g] * sh_act[2 * H + g]);
            hreg = sh_act[3 * H + g] * tanhf_(creg);
            sh_h[g] = hreg;
            hs_out[(size_t)t * H + g] = hreg;
        }
        __syncthreads();
    }
    if (g < H) { state[b * 2 * H + g] = hreg; state[b * 2 * H + H + g] = creg; }
}

// ---------------- Layer 1 scan over one chunk ----------------
__global__ __launch_bounds__(512, 2) void lstm_l1(
    const float* __restrict__ hs0, const float* __restrict__ Wih,
    const float* __restrict__ Whh, const float* __restrict__ bih,
    const float* __restrict__ bhh, float* __restrict__ state,
    int tc, int chunk)
{
    const int b = blockIdx.x;
    const int g = threadIdx.x;

    __shared__ alignas(16) float sh_h0[TS * H];      // 16 KB
    __shared__ alignas(16) float sh_gx[TS * GATES];  // 64 KB
    __shared__ alignas(16) float sh_h[H];
    __shared__ alignas(16) float sh_act[GATES];

    // resident: one row of W_hh_l1
    float wh[H];
    const float4* wr = (const float4*)(Whh + (size_t)g * H);
#pragma unroll
    for (int k = 0; k < H / 4; ++k) {
        float4 v = wr[k];
        wh[4*k] = v.x; wh[4*k+1] = v.y; wh[4*k+2] = v.z; wh[4*k+3] = v.w;
    }
    const float bias = bih[g] + bhh[g];

    float hreg = 0.f, creg = 0.f;
    if (g < H) {
        if (chunk) { hreg = state[b * 2 * H + g]; creg = state[b * 2 * H + H + g]; }
        sh_h[g] = hreg;
    }
    __syncthreads();

    const float* hsrc = hs0 + (size_t)b * tc * H;
    const float4* wihrow = (const float4*)(Wih + (size_t)g * H);

    const int nsub = tc / TS;
    for (int s = 0; s < nsub; ++s) {
        // stage 32 steps of h0 history (coalesced float4)
        const float4* src4 = (const float4*)(hsrc + (size_t)s * TS * H);
        float4* dst4 = (float4*)sh_h0;
        for (int i = g; i < TS * H / 4; i += 512) dst4[i] = src4[i];
        __syncthreads();

        // phase A: input projection gx1 for 32 steps at once.
        // W_ih_l1 streamed from L2 k-outer (4 regs live), 32 accumulators.
        float acc[TS];
#pragma unroll
        for (int t = 0; t < TS; ++t) acc[t] = bias;
        for (int k = 0; k < H / 4; ++k) {
            float4 w = wihrow[k];
            const float* hb = sh_h0 + 4 * k;
#pragma unroll
            for (int t = 0; t < TS; ++t) {
                float4 hv = *(const float4*)(hb + t * H);
                acc[t] = fmaf(w.x, hv.x,
                         fmaf(w.y, hv.y,
                         fmaf(w.z, hv.z,
                         fmaf(w.w, hv.w, acc[t]))));
            }
        }
#pragma unroll
        for (int t = 0; t < TS; ++t) sh_gx[t * GATES + g] = acc[t];
        __syncthreads();

        // phase B: 32 sequential recurrent steps
        for (int t = 0; t < TS; ++t) {
            float a0 = sh_gx[t * GATES + g], a1 = 0.f, a2 = 0.f, a3 = 0.f;
            const float4* h4 = (const float4*)sh_h;
#pragma unroll
            for (int k = 0; k < H / 4; ++k) {
                float4 v = h4[k];
                a0 = fmaf(wh[4*k],   v.x, a0); a1 = fmaf(wh[4*k+1], v.y, a1);
                a2 = fmaf(wh[4*k+2], v.z, a2); a3 = fmaf(wh[4*k+3], v.w, a3);
            }
            float pre = (a0 + a1) + (a2 + a3);
            float act = ((g >> 7) == 2) ? tanhf_(pre) : sigmoidf_(pre);
            sh_act[g] = act;
            __syncthreads();
            if (g < H) {
                creg = fmaf(sh_act[H + g], creg, sh_act[g] * sh_act[2 * H + g]);
                hreg = sh_act[3 * H + g] * tanhf_(creg);
                sh_h[g] = hreg;
            }
            __syncthreads();
        }
    }
    if (g < H) { state[b * 2 * H + g] = hreg; state[b * 2 * H + H + g] = creg; }
}

// ---------------- Output projection ----------------
__global__ void out_proj(const float* __restrict__ state1,
                         const float* __restrict__ Wout,
                         const float* __restrict__ bout,
                         float* __restrict__ out)
{
    const int b = blockIdx.x, j = threadIdx.x;
    __shared__ float sh[H];
    if (j < H) sh[j] = state1[b * 2 * H + j];
    __syncthreads();
    if (j < 4) {
        float a = bout[j];
        for (int k = 0; k < H; ++k) a = fmaf(Wout[j * H + k], sh[k], a);
        out[b * 4 + j] = a;
    }
}

extern "C" void kernel_launch(void* const* d_in, const int* in_sizes, int n_in,
                              void* d_out, int out_size, void* d_ws, size_t ws_size,
                              hipStream_t stream)
{
    const float* x    = (const float*)d_in[0];
    const float* Wih0 = (const float*)d_in[1];
    const float* Whh0 = (const float*)d_in[2];
    const float* bih0 = (const float*)d_in[3];
    const float* bhh0 = (const float*)d_in[4];
    const float* Wih1 = (const float*)d_in[5];
    const float* Whh1 = (const float*)d_in[6];
    const float* bih1 = (const float*)d_in[7];
    const float* bhh1 = (const float*)d_in[8];
    const float* Wout = (const float*)d_in[9];
    const float* bout = (const float*)d_in[10];

    // pick largest chunk that fits the workspace (deterministic: ws_size fixed)
    int tc = 32;
    for (int cand = TCMAX; cand >= 32; cand >>= 1) {
        size_t need = (size_t)B_ * cand * H * 4 + (size_t)B_ * 2 * H * 4 * 2;
        if (need <= ws_size) { tc = cand; break; }
    }

    float* ws  = (float*)d_ws;
    float* hs0 = ws;                              // B_*tc*H
    float* st0 = ws + (size_t)B_ * tc * H;        // B_*2*H
    float* st1 = st0 + (size_t)B_ * 2 * H;        // B_*2*H

    const int nchunks = T_ / tc;
    for (int c = 0; c < nchunks; ++c) {
        lstm_l0<<<B_, 512, 0, stream>>>(x, Wih0, Whh0, bih0, bhh0, hs0, st0, tc, c);
        lstm_l1<<<B_, 512, 0, stream>>>(hs0, Wih1, Whh1, bih1, bhh1, st1, tc, c);
    }
    out_proj<<<B_, 128, 0, stream>>>(st1, Wout, bout, (float*)d_out);
}